// Round 12
// baseline (187.086 us; speedup 1.0000x reference)
//
#include <hip/hip_runtime.h>
#include <math.h>

// Problem dims (fixed by setup_inputs)
#define BBATCH 8
#define TT    4096
#define II    64
#define DD    128
#define OO    64
#define PP    8
#define NTOT  (BBATCH * TT)      // 32768
#define RPB   32                 // rows per block == scan chunk
#define NBLK  (NTOT / RPB)       // 1024 blocks == resident capacity (4/CU)
#define CPB   (TT / RPB)         // 128 chunks per batch

// LDS layout (bytes)
#define PAN_H  0                 // h panel: 128 cols x 72 B (32 rows bf16 + pad)
#define PAN_Z  9216              // z panel: same (ends 18432)
#define XT     18432             // phase A: x-tile 32 rows x 136 B (ends 22784)
#define HTB    18432             // scan/C: 32 rows x 264 B (overlays dead XT), ends 26880
#define LDSSZ  26880             // 6 blocks/CU by LDS; VGPR caps at 4 -> grid 1024 resident

typedef short bf16x8 __attribute__((ext_vector_type(8)));
typedef float f32x4  __attribute__((ext_vector_type(4)));

__device__ __forceinline__ unsigned short f2bf(float f) {
    union { float f; unsigned int u; } v; v.f = f;
    unsigned int r = v.u + 0x7fffu + ((v.u >> 16) & 1u);   // RNE
    return (unsigned short)(r >> 16);
}

__device__ __forceinline__ float bf2f(unsigned short b) {
    union { float f; unsigned int u; } v; v.u = ((unsigned int)b) << 16;
    return v.f;
}

// pack the 8 piecewise-linear knot weights for one scalar into 8 bf16
// (A-fragment k-block of 8 == one input's 8 knots)
__device__ __forceinline__ bf16x8 apl_frag(float xv) {
    float t = fminf(fmaxf((xv + 1.0f) * 3.5f, 0.0f), 7.0f);
    int idx = (int)t; if (idx > 6) idx = 6;
    float frac = t - (float)idx;
    const unsigned int b0 = f2bf(1.0f - frac);
    const unsigned int b1 = f2bf(frac);
    const int q = idx >> 1;
    const bool odd = (idx & 1) != 0;
    const unsigned int vA = odd ? (b0 << 16) : (b0 | (b1 << 16));
    const unsigned int vB = odd ? b1 : 0u;
    union { uint4 u; bf16x8 v; } cv;
    cv.u.x = (q == 0) ? vA : 0u;
    cv.u.y = (q == 1) ? vA : ((q == 0) ? vB : 0u);
    cv.u.z = (q == 2) ? vA : ((q == 1) ? vB : 0u);
    cv.u.w = (q == 3) ? vA : ((q == 2) ? vB : 0u);
    return cv.v;
}

// ---------------------------------------------------------------------------
// prep_tables: K-tiled B operands.
//   Vt2[c][col][kk]: c = k>>5 (16 chunks), col 0..255 (0-127 h, 128-255 z), kk = k&31
//   Ot2[c][col][kk]: c = k>>5 (32 chunks), col 0..63
// A wave's fragment loads for one (chunk, 16-col tile) are 1 KB contiguous.
// Blocks 512..639 also zero the 1024 lookback flags.
// ---------------------------------------------------------------------------
__global__ __launch_bounds__(256) void prep_tables(
    const float* __restrict__ hv, const float* __restrict__ zv,
    const float* __restrict__ ov,
    unsigned short* __restrict__ Vt2, unsigned short* __restrict__ Ot2,
    unsigned int* __restrict__ flags)
{
    const int b = blockIdx.x, tid = threadIdx.x;
    if (b < 512) {
        const int k = b, c = tid;
        float v = (c < 128) ? hv[(size_t)k * 128 + c] : zv[(size_t)k * 128 + (c - 128)];
        Vt2[((size_t)(k >> 5) * 256 + c) * 32 + (k & 31)] = f2bf(v);
    } else {
        const int k = (b - 512) * 4 + (tid >> 6), c = tid & 63;
        Ot2[((size_t)(k >> 5) * 64 + c) * 32 + (k & 31)] = f2bf(ov[(size_t)k * 64 + c]);
        if (b < 640) flags[(size_t)(b - 512) * 256 + tid] = 0u;
    }
}

// ---------------------------------------------------------------------------
// Fused, staging-free: APL1 GEMM (A packed in-lane from LDS x-tile, B loaded
// straight from L2-resident K-tiled tables, coalesced 1KB/instr) ->
// aggregates -> decoupled lookback -> prefix -> in-LDS z-mix scan (ht) ->
// APL2 GEMM -> y.  1024 blocks x 256 threads, 4 blocks/CU.
// ---------------------------------------------------------------------------
__global__ __launch_bounds__(256, 4) void fused_all(
    const float* __restrict__ x, const float* __restrict__ h0,
    const unsigned short* __restrict__ Vt2, const unsigned short* __restrict__ Ot2,
    float* __restrict__ agg, unsigned int* __restrict__ flags,
    float* __restrict__ ht_out, float* __restrict__ y)
{
    __shared__ unsigned char smem[LDSSZ];
    const int tid = threadIdx.x;
    const int wave = tid >> 6, lane = tid & 63;
    const int m = lane & 15, u = lane >> 4;   // MFMA fragment coords
    const int g = blockIdx.x;                 // chunk id
    const int n0 = g * RPB;
    const int b = g >> 7, lb = g & 127;       // batch, local chunk (lb preds)

    // ---- stage x-tile (32 rows x 64 fp32 -> bf16) into XT, coalesced ----
    {
        const int row = tid >> 3, c0 = (tid & 7) * 8;
        const float* xr = x + (size_t)(n0 + row) * II + c0;
        #pragma unroll
        for (int j = 0; j < 2; ++j) {
            float4 v = *(const float4*)(xr + 4 * j);
            ushort4 p;
            p.x = f2bf(v.x); p.y = f2bf(v.y); p.z = f2bf(v.z); p.w = f2bf(v.w);
            *(ushort4*)(smem + XT + row * 136 + (c0 + 4 * j) * 2) = p;
        }
    }
    __syncthreads();

    // ---------------- Phase A: C(32 x 256) = W(32 x 512) x Vt2^T ------------
    const int colbase = wave * 64;            // waves 0,1: h cols; 2,3: z cols
    f32x4 acc[2][4];
    #pragma unroll
    for (int tr = 0; tr < 2; ++tr)
        #pragma unroll
        for (int tc = 0; tc < 4; ++tc)
            acc[tr][tc] = (f32x4){0.f, 0.f, 0.f, 0.f};

    {
        const unsigned char* vtb = (const unsigned char*)Vt2;
        #pragma unroll 4
        for (int c = 0; c < 16; ++c) {
            bf16x8 a[2], bb[4];
            #pragma unroll
            for (int tc = 0; tc < 4; ++tc)
                bb[tc] = *(const bf16x8*)(vtb + (size_t)(c * 256 + colbase + tc * 16 + m) * 64 + u * 16);
            #pragma unroll
            for (int tr = 0; tr < 2; ++tr) {
                float xv = bf2f(*(const unsigned short*)(smem + XT + (tr * 16 + m) * 136 + (c * 4 + u) * 2));
                a[tr] = apl_frag(xv);
            }
            #pragma unroll
            for (int tr = 0; tr < 2; ++tr)
                #pragma unroll
                for (int tc = 0; tc < 4; ++tc)
                    acc[tr][tc] = __builtin_amdgcn_mfma_f32_16x16x32_bf16(a[tr], bb[tc], acc[tr][tc], 0, 0, 0);
        }
    }

    // aggregates over 32 rows (waves 0,1 hold h cols 0..127) -> global
    if (wave < 2) {
        #pragma unroll
        for (int tc = 0; tc < 4; ++tc) {
            float s = 0.0f;
            #pragma unroll
            for (int tr = 0; tr < 2; ++tr) {
                f32x4 v = acc[tr][tc];
                s += v[0] + v[1] + v[2] + v[3];
            }
            s += __shfl_xor(s, 16);
            s += __shfl_xor(s, 32);
            if ((lane >> 4) == 0)
                __hip_atomic_store(&agg[(size_t)g * 128 + colbase + tc * 16 + lane], s,
                                   __ATOMIC_RELAXED, __HIP_MEMORY_SCOPE_AGENT);
        }
    }

    // panels: C/D layout col=lane&15 (+tile), row=(lane>>4)*4+reg (+tile)
    #pragma unroll
    for (int tr = 0; tr < 2; ++tr) {
        #pragma unroll
        for (int tc = 0; tc < 4; ++tc) {
            const int col = colbase + tc * 16 + m;
            const int r0 = tr * 16 + u * 4;
            f32x4 v = acc[tr][tc];
            ushort4 p4;
            if (col < 128) {
                p4.x = f2bf(v[0]); p4.y = f2bf(v[1]);
                p4.z = f2bf(v[2]); p4.w = f2bf(v[3]);
                *(ushort4*)(smem + PAN_H + col * 72 + r0 * 2) = p4;
            } else {
                p4.x = f2bf(1.0f / (1.0f + __expf(-v[0])));
                p4.y = f2bf(1.0f / (1.0f + __expf(-v[1])));
                p4.z = f2bf(1.0f / (1.0f + __expf(-v[2])));
                p4.w = f2bf(1.0f / (1.0f + __expf(-v[3])));
                *(ushort4*)(smem + PAN_Z + (col - 128) * 72 + r0 * 2) = p4;
            }
        }
    }

    __syncthreads();                     // agg stores drained + panels visible
    if (tid == 0) {
        __threadfence();
        __hip_atomic_store(&flags[(size_t)g * 32], 1u,
                           __ATOMIC_RELEASE, __HIP_MEMORY_SCOPE_AGENT);
    }

    // ---------- decoupled lookback: parallel poll of same-batch preds -------
    if (tid < lb) {
        const unsigned int* fp = flags + (size_t)(b * CPB + tid) * 32;
        while (__hip_atomic_load(fp, __ATOMIC_ACQUIRE, __HIP_MEMORY_SCOPE_AGENT) == 0u)
            __builtin_amdgcn_s_sleep(1);
    }
    __syncthreads();                     // all preds done

    // ---------------- prefix + in-LDS z-mix scan -> ht ----------------------
    if (tid < 128) {
        const int d = tid;
        float run = h0[(size_t)b * 128 + d];
        const float* ap = agg + (size_t)(b * CPB) * 128 + d;
        float s0 = 0.f, s1 = 0.f, s2 = 0.f, s3 = 0.f;
        int k = 0;
        for (; k + 4 <= lb; k += 4) {
            s0 += __hip_atomic_load(ap + (size_t)(k + 0) * 128, __ATOMIC_RELAXED, __HIP_MEMORY_SCOPE_AGENT);
            s1 += __hip_atomic_load(ap + (size_t)(k + 1) * 128, __ATOMIC_RELAXED, __HIP_MEMORY_SCOPE_AGENT);
            s2 += __hip_atomic_load(ap + (size_t)(k + 2) * 128, __ATOMIC_RELAXED, __HIP_MEMORY_SCOPE_AGENT);
            s3 += __hip_atomic_load(ap + (size_t)(k + 3) * 128, __ATOMIC_RELAXED, __HIP_MEMORY_SCOPE_AGENT);
        }
        for (; k < lb; ++k)
            s0 += __hip_atomic_load(ap + (size_t)k * 128, __ATOMIC_RELAXED, __HIP_MEMORY_SCOPE_AGENT);
        run += (s0 + s1) + (s2 + s3);
        #pragma unroll
        for (int rq = 0; rq < 8; ++rq) {
            ushort4 h4 = *(const ushort4*)(smem + PAN_H + d * 72 + rq * 8);
            ushort4 z4 = *(const ushort4*)(smem + PAN_Z + d * 72 + rq * 8);
            const unsigned short* hp = (const unsigned short*)&h4;
            const unsigned short* zp = (const unsigned short*)&z4;
            #pragma unroll
            for (int kk = 0; kk < 4; ++kk) {
                const int r = rq * 4 + kk;
                float hb = bf2f(hp[kk]);
                float zt = bf2f(zp[kk]);
                run += hb;
                float htv = (1.0f - zt) * run + zt * hb;
                ht_out[(size_t)(n0 + r) * DD + d] = htv;
                *(unsigned short*)(smem + HTB + r * 264 + d * 2) = f2bf(htv);
            }
        }
    }
    __syncthreads();                     // HTB ready

    // ---------------- Phase C: y(32 x 64) = W2(32 x 1024) x Ot2^T -----------
    const int wr = wave >> 1, wc = wave & 1;  // row-tile, col-half
    f32x4 acc2[2];
    acc2[0] = (f32x4){0.f, 0.f, 0.f, 0.f};
    acc2[1] = (f32x4){0.f, 0.f, 0.f, 0.f};

    {
        const unsigned char* otb = (const unsigned char*)Ot2;
        #pragma unroll 4
        for (int c = 0; c < 32; ++c) {
            bf16x8 b2[2];
            #pragma unroll
            for (int tc = 0; tc < 2; ++tc)
                b2[tc] = *(const bf16x8*)(otb + (size_t)(c * 64 + wc * 32 + tc * 16 + m) * 64 + u * 16);
            float htv = bf2f(*(const unsigned short*)(smem + HTB + (wr * 16 + m) * 264 + (c * 4 + u) * 2));
            bf16x8 a2 = apl_frag(htv);
            #pragma unroll
            for (int tc = 0; tc < 2; ++tc)
                acc2[tc] = __builtin_amdgcn_mfma_f32_16x16x32_bf16(a2, b2[tc], acc2[tc], 0, 0, 0);
        }
    }

    #pragma unroll
    for (int tc = 0; tc < 2; ++tc) {
        const int col = wc * 32 + tc * 16 + m;
        const int n = n0 + wr * 16 + u * 4;
        f32x4 v = acc2[tc];
        #pragma unroll
        for (int rg = 0; rg < 4; ++rg)
            y[(size_t)(n + rg) * OO + col] = v[rg];
    }
}

// ---------------------------------------------------------------------------
extern "C" void kernel_launch(void* const* d_in, const int* in_sizes, int n_in,
                              void* d_out, int out_size, void* d_ws, size_t ws_size,
                              hipStream_t stream) {
    const float* x  = (const float*)d_in[0];   // (B,T,I)
    const float* h0 = (const float*)d_in[1];   // (B,D)
    const float* zv = (const float*)d_in[2];   // (I,P,D)
    const float* hv = (const float*)d_in[3];   // (I,P,D)
    const float* ov = (const float*)d_in[4];   // (D,P,O)

    float* y  = (float*)d_out;                           // (B,T,O)
    float* ht = (float*)d_out + (size_t)NTOT * OO;       // (B,T,D)

    unsigned int* flags = (unsigned int*)d_ws;                     // 1024*32 u32 = 128 KB
    float* agg = (float*)(flags + (size_t)NBLK * 32);              // 1024*128 f32 = 512 KB
    unsigned short* Vt2 = (unsigned short*)(agg + (size_t)NBLK * 128);  // 16*256*32
    unsigned short* Ot2 = Vt2 + 512 * 256;                              // 32*64*32

    prep_tables<<<768, 256, 0, stream>>>(hv, zv, ov, Vt2, Ot2, flags);
    fused_all<<<NBLK, 256, 0, stream>>>(x, h0, Vt2, Ot2, agg, flags, ht, y);
}